// Round 8
// baseline (580.220 us; speedup 1.0000x reference)
//
#include <hip/hip_runtime.h>
#include <cstdint>

// ---------------- types ----------------
typedef __bf16 bf16_t;
typedef __bf16 bf16x8 __attribute__((ext_vector_type(8)));
typedef __bf16 bf16x4 __attribute__((ext_vector_type(4)));
typedef float  f32x4  __attribute__((ext_vector_type(4)));
typedef bf16x8 __attribute__((may_alias)) bf16x8a;
typedef bf16x4 __attribute__((may_alias)) bf16x4a;
typedef f32x4  __attribute__((may_alias)) f32x4a;

#define S_LEN 2048
#define HDIM  2048
#define NHEAD 16
#define HD    128
#define TSD   512
#define BROWS 4096   // B * S
#define KIDX  459    // K_IDX - 1
#define KCAT  2560   // HDIM + TSD (fused QKV K-depth)

__device__ __forceinline__ f32x4 mfma_bf16(bf16x8 a, bf16x8 b, f32x4 c) {
  return __builtin_amdgcn_mfma_f32_16x16x32_bf16(a, b, c, 0, 0, 0);
}

__device__ __forceinline__ void gld_lds16(const bf16_t* g, bf16_t* l) {
  __builtin_amdgcn_global_load_lds(
      (__attribute__((address_space(1))) void*)(void*)const_cast<bf16_t*>(g),
      (__attribute__((address_space(3))) void*)(void*)(l), 16, 0, 0);
}

__device__ __forceinline__ uint32_t pk2(float a, float b) {
  union { bf16_t h; uint16_t u; } ua, ub;
  ua.h = (bf16_t)a; ub.h = (bf16_t)b;
  return (uint32_t)ua.u | ((uint32_t)ub.u << 16);
}

// ---------------- elementwise convert fp32 -> bf16 ----------------
__global__ void k_cvt(const float* __restrict__ in, bf16_t* __restrict__ out, int n) {
  int i = (blockIdx.x * 256 + threadIdx.x) * 4;
  if (i >= n) return;
  f32x4 v = *(const f32x4a*)(in + i);
  bf16x4 o = { (bf16_t)v.x, (bf16_t)v.y, (bf16_t)v.z, (bf16_t)v.w };
  *(bf16x4a*)(out + i) = o;
}

// ---------------- transpose + convert: out[c][koff + r] = in[r][c] ----------------
__global__ void k_transpose(const float* __restrict__ in, bf16_t* __restrict__ out,
                            int ldin, int ldout, int koff) {
  __shared__ float tile[32][33];
  int c0 = blockIdx.x * 32, r0 = blockIdx.y * 32;
  int tx = threadIdx.x, ty = threadIdx.y;
  for (int i = ty; i < 32; i += 8)
    tile[i][tx] = in[(size_t)(r0 + i) * ldin + c0 + tx];
  __syncthreads();
  for (int i = ty; i < 32; i += 8)
    out[(size_t)(c0 + i) * ldout + koff + r0 + tx] = (bf16_t)tile[tx][i];
}

// ---------------- multi-job transpose: one dispatch for all weight panels ----
struct TJobs {
  const float* src[7];
  bf16_t*      dst[7];
  int ldin[7], ldout[7], koff[7], nbx[7], nby[7];
};

__global__ void k_transpose_multi(TJobs jobs) {
  const int z = blockIdx.z;
  if ((int)blockIdx.x >= jobs.nbx[z] || (int)blockIdx.y >= jobs.nby[z]) return;
  __shared__ float tile[32][33];
  const float* in  = jobs.src[z];
  bf16_t*      out = jobs.dst[z];
  const int ldin = jobs.ldin[z], ldout = jobs.ldout[z], koff = jobs.koff[z];
  int c0 = blockIdx.x * 32, r0 = blockIdx.y * 32;
  int tx = threadIdx.x, ty = threadIdx.y;
  for (int i = ty; i < 32; i += 8)
    tile[i][tx] = in[(size_t)(r0 + i) * ldin + c0 + tx];
  __syncthreads();
  for (int i = ty; i < 32; i += 8)
    out[(size_t)(c0 + i) * ldout + koff + r0 + tx] = (bf16_t)tile[tx][i];
}

// ---------------- bf16 transpose: vbuf [bh][s][d] -> vtb [bh][d][s] ----------------
__global__ void k_vtrans(const bf16_t* __restrict__ in, bf16_t* __restrict__ out) {
  __shared__ bf16_t t[64][72];
  int s0 = blockIdx.x * 64, d0 = blockIdx.y * 64, bh = blockIdx.z;
  const bf16_t* src = in + (size_t)bh * S_LEN * HD;
  bf16_t* dst = out + (size_t)bh * HD * S_LEN;
  int tid = threadIdx.x;
  for (int g = tid; g < 512; g += 256) {
    int r = g >> 3, cc = g & 7;
    *(bf16x8a*)&t[r][cc * 8] = *(const bf16x8a*)(src + (size_t)(s0 + r) * HD + d0 + cc * 8);
  }
  __syncthreads();
  for (int g = tid; g < 512; g += 256) {
    int dr = g >> 3, sc = g & 7;
    bf16x8 v;
#pragma unroll
    for (int j = 0; j < 8; j++) v[j] = t[sc * 8 + j][dr];
    *(bf16x8a*)(dst + (size_t)(d0 + dr) * S_LEN + s0 + sc * 8) = v;
  }
}

// ============ GEMM core: simple 2-barrier loop, BK=64 (v13) ============
// Round-7 confirmed the simple structure beats hand-pipelining (m131-m141).
// v13 halves the per-block barrier/drain count by staging K=64 per tile and
// running two MFMA k-subtiles (kk=0,1) per stage. LDS granule-linear:
// granule G (16 B) lives at LDS offset G*16; thread tid stages granules
// G = tid + 256*j; wave-uniform dest base = j*2048 + w*512 elements.

// ---------------- generic GEMM: A[M][K] x Bt[N][K] -> f32 out ----------------
template<int BM>
__global__ __launch_bounds__(256)
void k_gemm(const bf16_t* __restrict__ A, const bf16_t* __restrict__ Bt,
            float* __restrict__ outF, int M, int N, int K)
{
  __shared__ __align__(16) bf16_t As[BM * 64];
  __shared__ __align__(16) bf16_t Bs[128 * 64];
  const int tid  = threadIdx.x;
  const int lane = tid & 63, w = tid >> 6;
  const int quad = lane >> 4, l15 = lane & 15;
  const int m0 = blockIdx.y * BM, n0 = blockIdx.x * 128;
  constexpr int MI = BM / 32;             // m-frags per wave (4 or 2)
  constexpr int AG = BM / 32;             // A gld calls per thread (4 or 2)
  const int wm = (w >> 1) * (BM / 2);
  const int wn = (w & 1) * 64;

  // staging source offsets (element units, 32-bit)
  int asrc[AG], bsrc[4];
#pragma unroll
  for (int j = 0; j < AG; j++) {
    int G = tid + 256 * j;
    asrc[j] = (m0 + (G >> 3)) * K + (G & 7) * 8;
  }
#pragma unroll
  for (int j = 0; j < 4; j++) {
    int G = tid + 256 * j;
    bsrc[j] = (n0 + (G >> 3)) * K + (G & 7) * 8;
  }

  f32x4 acc[MI][4];
#pragma unroll
  for (int i = 0; i < MI; i++)
#pragma unroll
    for (int j = 0; j < 4; j++) { f32x4 z = {0.f,0.f,0.f,0.f}; acc[i][j] = z; }

  for (int k0 = 0; k0 < K; k0 += 64) {
    __syncthreads();
#pragma unroll
    for (int j = 0; j < AG; j++)
      gld_lds16(A + asrc[j] + k0, As + j * 2048 + w * 512);
#pragma unroll
    for (int j = 0; j < 4; j++)
      gld_lds16(Bt + bsrc[j] + k0, Bs + j * 2048 + w * 512);
    __syncthreads();
#pragma unroll
    for (int kk = 0; kk < 2; kk++) {
      bf16x8 af[MI], bv[4];
#pragma unroll
      for (int i = 0; i < MI; i++)
        af[i] = *(const bf16x8a*)&As[(wm + i * 16 + l15) * 64 + kk * 32 + quad * 8];
#pragma unroll
      for (int j = 0; j < 4; j++)
        bv[j] = *(const bf16x8a*)&Bs[(wn + j * 16 + l15) * 64 + kk * 32 + quad * 8];
#pragma unroll
      for (int i = 0; i < MI; i++)
#pragma unroll
        for (int j = 0; j < 4; j++)
          acc[i][j] = mfma_bf16(af[i], bv[j], acc[i][j]);
    }
  }

#pragma unroll
  for (int i = 0; i < MI; i++)
#pragma unroll
    for (int j = 0; j < 4; j++)
#pragma unroll
      for (int r = 0; r < 4; r++) {
        int row = m0 + wm + i * 16 + quad * 4 + r;
        int col = n0 + wn + j * 16 + l15;
        outF[(size_t)row * N + col] = acc[i][j][r];
      }
}

// ---------------- fused QKV GEMM (BK=64 core, K-concat addend, RoPE) ----
__global__ __launch_bounds__(256)
void k_gemm_qkv(const bf16_t* __restrict__ hsB, const bf16_t* __restrict__ tsf,
                const bf16_t* __restrict__ wcat, bf16_t* __restrict__ outQKV,
                const float* __restrict__ tabC, const float* __restrict__ tabS)
{
  __shared__ __align__(16) bf16_t As[128 * 64];
  __shared__ __align__(16) bf16_t Bs[128 * 64];
  const int tid  = threadIdx.x;
  const int lane = tid & 63, w = tid >> 6;
  const int quad = lane >> 4, l15 = lane & 15;
  const int wi = blockIdx.x >> 4;                 // 0=Q 1=K 2=V
  const int n0 = (blockIdx.x & 15) * 128;         // head tile within weight
  const int m0 = blockIdx.y * 128;
  const int wm = (w >> 1) * 64;
  const bf16_t* Bt = wcat + (size_t)wi * HDIM * KCAT;
  bf16_t* outp = outQKV + (size_t)wi * 8388608;

  // staging source offsets (element units, 32-bit)
  int aoffh[4], aofft[4], boff[4];
#pragma unroll
  for (int j = 0; j < 4; j++) {
    int G = tid + 256 * j;
    int row = G >> 3, cg = G & 7;
    aoffh[j] = (m0 + row) * HDIM + cg * 8;
    aofft[j] = (m0 + row) * TSD  + cg * 8;
    boff[j]  = (n0 + row) * KCAT + cg * 8;
  }

  // paired column mapping (bijective over the 128-col tile)
  int col2[4];
#pragma unroll
  for (int j = 0; j < 4; j++)
    col2[j] = (w & 1) * 32 + (j & 1) * 16 + (j >> 1) * 64 + l15;

  f32x4 acc[4][4];
#pragma unroll
  for (int i = 0; i < 4; i++)
#pragma unroll
    for (int j = 0; j < 4; j++) { f32x4 z = {0.f,0.f,0.f,0.f}; acc[i][j] = z; }

  for (int k0 = 0; k0 < KCAT; k0 += 64) {
    __syncthreads();
    if (k0 < HDIM) {
#pragma unroll
      for (int j = 0; j < 4; j++)
        gld_lds16(hsB + aoffh[j] + k0, As + j * 2048 + w * 512);
    } else {
#pragma unroll
      for (int j = 0; j < 4; j++)
        gld_lds16(tsf + aofft[j] + (k0 - HDIM), As + j * 2048 + w * 512);
    }
#pragma unroll
    for (int j = 0; j < 4; j++)
      gld_lds16(Bt + boff[j] + k0, Bs + j * 2048 + w * 512);
    __syncthreads();
#pragma unroll
    for (int kk = 0; kk < 2; kk++) {
      bf16x8 af[4], bv[4];
#pragma unroll
      for (int i = 0; i < 4; i++)
        af[i] = *(const bf16x8a*)&As[(wm + i * 16 + l15) * 64 + kk * 32 + quad * 8];
#pragma unroll
      for (int j = 0; j < 4; j++)
        bv[j] = *(const bf16x8a*)&Bs[col2[j] * 64 + kk * 32 + quad * 8];
#pragma unroll
      for (int i = 0; i < 4; i++)
#pragma unroll
        for (int j = 0; j < 4; j++)
          acc[i][j] = mfma_bf16(af[i], bv[j], acc[i][j]);
    }
  }

  const int h = n0 >> 7;   // head index (n-tile == head)
  if (wi == 2) {
    // V: reshape store [b][h][s][d]
#pragma unroll
    for (int i = 0; i < 4; i++)
#pragma unroll
      for (int r = 0; r < 4; r++) {
        int row = m0 + wm + i * 16 + quad * 4 + r;
        int s = row & (S_LEN - 1), b = row >> 11;
        size_t obase = (((size_t)(b * NHEAD + h) * S_LEN) + s) * HD;
#pragma unroll
        for (int j = 0; j < 4; j++)
          outp[obase + col2[j]] = (bf16_t)acc[i][j][r];
      }
  } else {
    // Q/K: RoPE in f32, then store both halves of each (d, d+64) pair
#pragma unroll
    for (int i = 0; i < 4; i++)
#pragma unroll
      for (int r = 0; r < 4; r++) {
        int row = m0 + wm + i * 16 + quad * 4 + r;
        int s = row & (S_LEN - 1), b = row >> 11;
        size_t obase = (((size_t)(b * NHEAD + h) * S_LEN) + s) * HD;
#pragma unroll
        for (int j = 0; j < 2; j++) {
          int d = (w & 1) * 32 + j * 16 + l15;   // < 64
          float lo = acc[i][j][r];
          float hi = acc[i][j + 2][r];
          float c  = tabC[s * 64 + d];
          float sn = tabS[s * 64 + d];
          outp[obase + d]      = (bf16_t)(lo * c - hi * sn);
          outp[obase + d + 64] = (bf16_t)(hi * c + lo * sn);
        }
      }
  }
}

// ---------------- blend + rmsnorm + kth-threshold + relu ----------------
__global__ __launch_bounds__(256)
void k_tsproc(const float* __restrict__ ts, const float* __restrict__ lte,
              const float* __restrict__ wn, bf16_t* __restrict__ tsf)
{
  __shared__ float sv[TSD];
  __shared__ float red[4];
  int row = blockIdx.x;
  int t = threadIdx.x;
  const float* tr = ts  + (size_t)row * TSD;
  const float* lr = lte + (size_t)row * TSD;
  float v0 = 0.5f * tr[t] + 0.5f * lr[t];
  float v1 = 0.5f * tr[t + 256] + 0.5f * lr[t + 256];
  float ss = v0 * v0 + v1 * v1;
#pragma unroll
  for (int o = 32; o > 0; o >>= 1) ss += __shfl_down(ss, o);
  int lane = t & 63, wv = t >> 6;
  if (lane == 0) red[wv] = ss;
  __syncthreads();
  float tot = red[0] + red[1] + red[2] + red[3];
  float scl = rsqrtf(tot * (1.0f / TSD) + 1e-6f);
  float n0 = v0 * scl * wn[t];
  float n1 = v1 * scl * wn[t + 256];
  sv[t] = n0; sv[t + 256] = n1;
  __syncthreads();
  for (int k = 2; k <= TSD; k <<= 1) {
    for (int j = k >> 1; j > 0; j >>= 1) {
#pragma unroll
      for (int u = 0; u < 2; u++) {
        int idx = t + u * 256;
        int ixj = idx ^ j;
        if (ixj > idx) {
          float a = sv[idx], b = sv[ixj];
          bool up = ((idx & k) == 0);
          if ((a > b) == up) { sv[idx] = b; sv[ixj] = a; }
        }
      }
      __syncthreads();
    }
  }
  float kth = sv[KIDX];
  tsf[(size_t)row * TSD + t]       = (bf16_t)fmaxf(n0 - kth, 0.0f);
  tsf[(size_t)row * TSD + t + 256] = (bf16_t)fmaxf(n1 - kth, 0.0f);
}

// ---------------- RoPE tables: tab[s][d] = cos/sin(s * 10000^(-2d/128)) ----------------
__global__ void k_ropetab(float* __restrict__ tabC, float* __restrict__ tabS) {
  int gid = blockIdx.x * 256 + threadIdx.x;   // 2048*64
  int d = gid & 63, s = gid >> 6;
  float inv = powf(10000.0f, (float)(-2 * d) * (1.0f / 128.0f));
  float sn, c;
  sincosf((float)s * inv, &sn, &c);
  tabC[gid] = c; tabS[gid] = sn;
}

// ---------------- flash attention v7 (causal) ----------------
// Q-tile 64 (4 waves x 16 q-rows), single 32 KB K/V LDS buffer staged via
// global_load_lds with pre-swizzled per-lane global source addresses
// (rule 21/m173: linear LDS dest, source XOR'd by the readers' involution).
// T13 defer-max + T5 setprio.
__global__ __launch_bounds__(256, 4)
void k_attn(const bf16_t* __restrict__ qb, const bf16_t* __restrict__ kb,
            const bf16_t* __restrict__ vtb, bf16_t* __restrict__ attnB)
{
  __shared__ __align__(16) bf16_t Kt[64 * 128];   // [key][d], swizzled granules
  __shared__ __align__(16) bf16_t Vt[128 * 64];   // [d][key], swizzled granules

  const int bid = blockIdx.x;
  const int bh  = (bid & 7) + 8 * (bid >> 8);     // same head -> same XCD (bid%8)
  static const int qmap[32] = {31,0,30,1,29,2,28,3,27,4,26,5,25,6,24,7,
                               23,8,22,9,21,10,20,11,19,12,18,13,17,14,16,15};
  const int q0 = qmap[((bid >> 3) + (bid >> 8)) & 31] * 64;

  const int tid = threadIdx.x;
  const int lane = tid & 63, w = tid >> 6;        // 4 waves
  const int quad = lane >> 4, l15 = lane & 15;

  const bf16_t* Q  = qb  + (size_t)bh * S_LEN * HD;
  const bf16_t* Kg = kb  + (size_t)bh * S_LEN * HD;
  const bf16_t* Vg = vtb + (size_t)bh * HD * S_LEN;   // [d][s]

  // Q B-fragments: wave w owns q-rows q0 + w*16 .. +15 (q = l15)
  bf16x8 qf[4];
  {
    const bf16_t* qrow = Q + (size_t)(q0 + w * 16 + l15) * HD;
#pragma unroll
    for (int c = 0; c < 4; c++)
      qf[c] = *(const bf16x8a*)(qrow + c * 32 + quad * 8);
  }

  // fragment read offsets within the buffers (swizzle folded in)
  int kfo[4];
#pragma unroll
  for (int c = 0; c < 4; c++)
    kfo[c] = l15 * 128 + (((c * 4 + quad) ^ (l15 & 7)) * 8);
  int vfo[2];
#pragma unroll
  for (int kc = 0; kc < 2; kc++)
    vfo[kc] = l15 * 64 + (((kc * 4 + quad) ^ (l15 & 7)) * 8);

  // global_load_lds staging: wave w, call j covers LDS granules
  // G = (w*4+j)*64 + lane (16 B each, linear dest). Source granule is
  // XOR-swizzled so that the fragment readers' XOR recovers it.
  int kSrc[4], vSrc[4];
#pragma unroll
  for (int j = 0; j < 4; j++) {
    int G  = (w * 4 + j) * 64 + lane;
    int r  = G >> 4, gl = G & 15;
    kSrc[j] = r * HD + ((gl ^ (r & 7)) * 8);
    int d  = G >> 3, vg = G & 7;
    vSrc[j] = d * S_LEN + ((vg ^ (d & 7)) * 8);
  }

  // bpermute source-lane byte addresses for P B-frag build
  const int addrA = 4 * (l15 + 32 * (quad & 1));   // j=0..3 source lane
  const int addrB = addrA + 64;                    // j=4..7 source lane
  const bool selHi = (quad >> 1) != 0;             // quads 2,3 use pk[2kc+1]

  f32x4 o[8];
#pragma unroll
  for (int t8 = 0; t8 < 8; t8++) { f32x4 z = {0.f,0.f,0.f,0.f}; o[t8] = z; }
  float m_i = -1e30f, l_i = 0.0f;

  const float scale = 0.08838834764831845f;   // 1/sqrt(128)
  const int kEnd = q0;                        // last k-tile start (keys <= q0+63)
  const int qrow_i = q0 + w * 16 + l15;       // this lane's q-row

  for (int k0 = 0; k0 <= kEnd; k0 += 64) {
    // stage tile k0 (buffer free: all waves passed barrier B of prev iter)
    {
      const bf16_t* Kgk = Kg + (size_t)k0 * HD;
      const bf16_t* Vgk = Vg + k0;
#pragma unroll
      for (int j = 0; j < 4; j++)
        gld_lds16(Kgk + kSrc[j], Kt + (w * 4 + j) * 512);
#pragma unroll
      for (int j = 0; j < 4; j++)
        gld_lds16(Vgk + vSrc[j], Vt + (w * 4 + j) * 512);
    }
    __syncthreads();   // barrier A: drains vmcnt, LDS writes visible

    // S^T = K Q^T : st[nt][r] = S[key = k0+nt*16+quad*4+r][q = qrow_i]
    f32x4 st_[4];
#pragma unroll
    for (int nt = 0; nt < 4; nt++) { f32x4 z = {0.f,0.f,0.f,0.f}; st_[nt] = z; }
    __builtin_amdgcn_s_setprio(1);
#pragma unroll
    for (int nt = 0; nt < 4; nt++)
#pragma unroll
      for (int c = 0; c < 4; c++) {
        bf16x8 kf = *(const bf16x8a*)(Kt + kfo[c] + nt * 2048);
        st_[nt] = mfma_bf16(kf, qf[c], st_[nt]);
      }
    __builtin_amdgcn_s_setprio(0);

    // scale + causal mask (only the diagonal tile k0 == q0 needs masking)
    if (k0 == q0) {
#pragma unroll
      for (int nt = 0; nt < 4; nt++)
#pragma unroll
        for (int r = 0; r < 4; r++) {
          int key = k0 + nt * 16 + quad * 4 + r;
          float v = st_[nt][r] * scale;
          st_[nt][r] = (key > qrow_i) ? -1e9f : v;
        }
    } else {
#pragma unroll
      for (int nt = 0; nt < 4; nt++)
#pragma unroll
        for (int r = 0; r < 4; r++)
          st_[nt][r] *= scale;
    }

    // online softmax: in-lane 16-value reduce + 2 cross-quad shuffles
    float mx = st_[0][0];
#pragma unroll
    for (int nt = 0; nt < 4; nt++)
#pragma unroll
      for (int r = 0; r < 4; r++) mx = fmaxf(mx, st_[nt][r]);
    mx = fmaxf(mx, __shfl_xor(mx, 16));
    mx = fmaxf(mx, __shfl_xor(mx, 32));

    // T13 defer-max: only rescale when the max grew by > 8 (P bounded by e^8)
    if (__ballot(mx > m_i + 8.0f)) {
      float mnew = fmaxf(m_i, mx);
      float alpha = __expf(m_i - mnew);
      m_i = mnew;
      l_i *= alpha;
#pragma unroll
      for (int t8 = 0; t8 < 8; t8++)
#pragma unroll
        for (int r = 0; r < 4; r++)
          o[t8][r] *= alpha;
    }

    float rs = 0.0f;
#pragma unroll
    for (int nt = 0; nt < 4; nt++)
#pragma unroll
      for (int r = 0; r < 4; r++) {
        float pv = __expf(st_[nt][r] - m_i);
        st_[nt][r] = pv;
        rs += pv;
      }
    rs += __shfl_xor(rs, 16);
    rs += __shfl_xor(rs, 32);
    l_i += rs;

    // pack P to bf16 pairs (per nt: regs 0,1 and 2,3)
    uint32_t pk[4][2];
#pragma unroll
    for (int nt = 0; nt < 4; nt++) {
      pk[nt][0] = pk2(st_[nt][0], st_[nt][1]);
      pk[nt][1] = pk2(st_[nt][2], st_[nt][3]);
    }

    // O^T += V^T * P : build P B-frag via bpermute, then MFMA over d-tiles
#pragma unroll
    for (int kc = 0; kc < 2; kc++) {
      uint32_t a0 = __builtin_amdgcn_ds_bpermute(addrA, (int)pk[2*kc][0]);
      uint32_t a1 = __builtin_amdgcn_ds_bpermute(addrA, (int)pk[2*kc][1]);
      uint32_t a2 = __builtin_amdgcn_ds_bpermute(addrB, (int)pk[2*kc][0]);
      uint32_t a3 = __builtin_amdgcn_ds_bpermute(addrB, (int)pk[2*kc][1]);
      uint32_t b0 = __builtin_amdgcn_ds_bpermute(addrA, (int)pk[2*kc+1][0]);
      uint32_t b1 = __builtin_amdgcn_ds_bpermute(addrA, (int)pk[2*kc+1][1]);
      uint32_t b2 = __builtin_amdgcn_ds_bpermute(addrB, (int)pk[2*kc+1][0]);
      uint32_t b3 = __builtin_amdgcn_ds_bpermute(addrB, (int)pk[2*kc+1][1]);
      union { bf16x8 v; uint32_t d[4]; } pf;
      pf.d[0] = selHi ? b0 : a0;
      pf.d[1] = selHi ? b1 : a1;
      pf.d[2] = selHi ? b2 : a2;
      pf.d[3] = selHi ? b3 : a3;
      __builtin_amdgcn_s_setprio(1);
#pragma unroll
      for (int t8 = 0; t8 < 8; t8++) {
        bf16x8 vf = *(const bf16x8a*)(Vt + vfo[kc] + t8 * 1024);
        o[t8] = mfma_bf16(vf, pf.v, o[t8]);
      }
      __builtin_amdgcn_s_setprio(0);
    }

    __syncthreads();   // barrier B: all waves done reading before next stage
  }

  // epilogue: O^T[d][q]: lane q = l15; d = t8*16 + quad*4 + r
  const int b = bh >> 4, h = bh & 15;
  const float rl = 1.0f / l_i;
  uint32_t* outp = (uint32_t*)(attnB + (size_t)(b * S_LEN + qrow_i) * HDIM + h * HD);
#pragma unroll
  for (int t8 = 0; t8 < 8; t8++)
#pragma unroll
    for (int pr = 0; pr < 2; pr++) {
      uint32_t v = pk2(o[t8][2*pr] * rl, o[t8][2*pr+1] * rl);
      outp[t8 * 8 + quad * 2 + pr] = v;
    }
}

// ---------------- launcher ----------------
extern "C" void kernel_launch(void* const* d_in, const int* in_sizes, int n_in,
                              void* d_out, int out_size, void* d_ws, size_t ws_size,
                              hipStream_t stream) {
  const float* hs    = (const float*)d_in[0];
  const float* lte   = (const float*)d_in[1];
  const float* Wq    = (const float*)d_in[2];
  const float* Wk    = (const float*)d_in[3];
  const float* Wv    = (const float*)d_in[4];
  const float* Wo    = (const float*)d_in[5];
  const float* Wts   = (const float*)d_in[6];
  const float* tsw   = (const float*)d_in[7];
  const float* Worig = (const float*)d_in[8];
  float* out = (float*)d_out;

  // workspace layout (total 121,634,816 B):
  //   hsB   16 MB  [4096][2048] bf16
  //   wT     8 MB  Wts^T then Wo^T
  //   tsB    8 MB  f32 ts; tabC/tabS alias after k_tsproc
  //   tsf    4 MB  [4096][512] bf16
  //   wcat  32 MB  3 x [2048][2560] bf16 (Q|K|V concat weights)
  //         -> dead after k_gemm_qkv; attnB (16 MB) + vtb (16 MB) alias here
  //   qbuf/kbuf/vbuf 3 x 16 MB
  char* p = (char*)d_ws;
  bf16_t* hsB   = (bf16_t*)(p);
  bf16_t* wT    = (bf16_t*)(p + 16777216);
  float*  tsB   = (float*)(p + 25165824);
  bf16_t* tsf   = (bf16_t*)(p + 33554432);
  bf16_t* wcat  = (bf16_t*)(p + 37748736);
  bf16_t* attnB = (bf16_t*)(p + 37748736);         // alias (wcat dead)
  bf16_t* vtb   = (bf16_t*)(p + 54525952);         // alias (wcat dead)
  bf16_t* qbuf  = (bf16_t*)(p + 71303168);
  bf16_t* kbuf  = (bf16_t*)(p + 88080384);
  bf16_t* vbuf  = (bf16_t*)(p + 104857600);
  float*  tabC  = tsB;                             // tsB dead after k_tsproc
  float*  tabS  = tsB + 131072;
  bf16_t* wcatQ = wcat;
  bf16_t* wcatK = wcat + (size_t)HDIM * KCAT;
  bf16_t* wcatV = wcat + (size_t)2 * HDIM * KCAT;

  k_cvt<<<8192, 256, 0, stream>>>(hs, hsB, BROWS * HDIM);
  k_transpose<<<dim3(16, 64), dim3(32, 8), 0, stream>>>(Wts, wT, 512, 2048, 0);
  // ts GEMM with BM=64: 256 blocks (1/CU) instead of 128 (0.5/CU)
  k_gemm<64><<<dim3(4, 64), 256, 0, stream>>>(hsB, wT, tsB, 4096, 512, 2048);
  k_tsproc<<<4096, 256, 0, stream>>>(tsB, lte, tsw, tsf);
  k_ropetab<<<512, 256, 0, stream>>>(tabC, tabS);

  // all weight transposes in ONE dispatch (z = job):
  //   0: Wq -> wcatQ       1: Wk -> wcatK       2: Wv -> wcatV
  //   3: Worig[:, 0:2048]    -> wcatQ koff 2048
  //   4: Worig[:,2048:4096]  -> wcatK koff 2048
  //   5: Worig[:,2048:4096]  -> wcatV koff 2048   (v_add = k_add)
  //   6: Wo -> wT  (wT's Wts^T already consumed by the ts GEMM)
  {
    TJobs J;
    J.src[0] = Wq;    J.dst[0] = wcatQ; J.ldin[0] = 2048; J.ldout[0] = KCAT; J.koff[0] = 0;    J.nbx[0] = 64; J.nby[0] = 64;
    J.src[1] = Wk;    J.dst[1] = wcatK; J.ldin[1] = 2048; J.ldout[1] = KCAT; J.koff[1] = 0;    J.nbx[1] = 64; J.nby[1] = 64;
    J.src[2] = Wv;    J.dst[2] = wcatV; J.ldin[2] = 2048; J.ldout[2] = KCAT; J.koff[2] = 0;    J.nbx[2] = 64; J.nby[2] = 64;
    J.src[3] = Worig;        J.dst[3] = wcatQ; J.ldin[3] = 6144; J.ldout[3] = KCAT; J.koff[3] = 2048; J.nbx[3] = 64; J.nby[3] = 16;
    J.src[4] = Worig + 2048; J.dst[4] = wcatK; J.ldin[4] = 6144; J.ldout[4] = KCAT; J.koff[4] = 2048; J.nbx[4] = 64; J.nby[4] = 16;
    J.src[5] = Worig + 2048; J.dst[5] = wcatV; J.ldin[5] = 6144; J.ldout[5] = KCAT; J.koff[5] = 2048; J.nbx[5] = 64; J.nby[5] = 16;
    J.src[6] = Wo;    J.dst[6] = wT;    J.ldin[6] = 2048; J.ldout[6] = 2048; J.koff[6] = 0;    J.nbx[6] = 64; J.nby[6] = 64;
    k_transpose_multi<<<dim3(64, 64, 7), dim3(32, 8), 0, stream>>>(J);
  }

  // fused QKV (+addend via K-concat, +RoPE epilogue)
  k_gemm_qkv<<<dim3(48, 32), 256, 0, stream>>>(hsB, tsf, wcat, qbuf, tabC, tabS);
  k_vtrans<<<dim3(32, 2, 32), 256, 0, stream>>>(vbuf, vtb);
  k_attn<<<1024, 256, 0, stream>>>(qbuf, kbuf, vtb, attnB);
  k_gemm<128><<<dim3(16, 32), 256, 0, stream>>>(attnB, wT, out, 4096, 2048, 2048);
}

// Round 9
// 523.583 us; speedup vs baseline: 1.1082x; 1.1082x over previous
//
#include <hip/hip_runtime.h>
#include <cstdint>

// ---------------- types ----------------
typedef __bf16 bf16_t;
typedef __bf16 bf16x8 __attribute__((ext_vector_type(8)));
typedef __bf16 bf16x4 __attribute__((ext_vector_type(4)));
typedef float  f32x4  __attribute__((ext_vector_type(4)));
typedef bf16x8 __attribute__((may_alias)) bf16x8a;
typedef bf16x4 __attribute__((may_alias)) bf16x4a;
typedef f32x4  __attribute__((may_alias)) f32x4a;

#define S_LEN 2048
#define HDIM  2048
#define NHEAD 16
#define HD    128
#define TSD   512
#define BROWS 4096   // B * S
#define KIDX  459    // K_IDX - 1
#define KCAT  2560   // HDIM + TSD (fused QKV K-depth)

__device__ __forceinline__ f32x4 mfma_bf16(bf16x8 a, bf16x8 b, f32x4 c) {
  return __builtin_amdgcn_mfma_f32_16x16x32_bf16(a, b, c, 0, 0, 0);
}

__device__ __forceinline__ void gld_lds16(const bf16_t* g, bf16_t* l) {
  __builtin_amdgcn_global_load_lds(
      (__attribute__((address_space(1))) void*)(void*)const_cast<bf16_t*>(g),
      (__attribute__((address_space(3))) void*)(void*)(l), 16, 0, 0);
}

__device__ __forceinline__ uint32_t pk2(float a, float b) {
  union { bf16_t h; uint16_t u; } ua, ub;
  ua.h = (bf16_t)a; ub.h = (bf16_t)b;
  return (uint32_t)ua.u | ((uint32_t)ub.u << 16);
}

// ---------------- elementwise convert fp32 -> bf16 ----------------
__global__ void k_cvt(const float* __restrict__ in, bf16_t* __restrict__ out, int n) {
  int i = (blockIdx.x * 256 + threadIdx.x) * 4;
  if (i >= n) return;
  f32x4 v = *(const f32x4a*)(in + i);
  bf16x4 o = { (bf16_t)v.x, (bf16_t)v.y, (bf16_t)v.z, (bf16_t)v.w };
  *(bf16x4a*)(out + i) = o;
}

// ---------------- transpose + convert: out[c][koff + r] = in[r][c] ----------------
__global__ void k_transpose(const float* __restrict__ in, bf16_t* __restrict__ out,
                            int ldin, int ldout, int koff) {
  __shared__ float tile[32][33];
  int c0 = blockIdx.x * 32, r0 = blockIdx.y * 32;
  int tx = threadIdx.x, ty = threadIdx.y;
  for (int i = ty; i < 32; i += 8)
    tile[i][tx] = in[(size_t)(r0 + i) * ldin + c0 + tx];
  __syncthreads();
  for (int i = ty; i < 32; i += 8)
    out[(size_t)(c0 + i) * ldout + koff + r0 + tx] = (bf16_t)tile[tx][i];
}

// ---------------- multi-job transpose: one dispatch for all weight panels ----
struct TJobs {
  const float* src[7];
  bf16_t*      dst[7];
  int ldin[7], ldout[7], koff[7], nbx[7], nby[7];
};

__global__ void k_transpose_multi(TJobs jobs) {
  const int z = blockIdx.z;
  if ((int)blockIdx.x >= jobs.nbx[z] || (int)blockIdx.y >= jobs.nby[z]) return;
  __shared__ float tile[32][33];
  const float* in  = jobs.src[z];
  bf16_t*      out = jobs.dst[z];
  const int ldin = jobs.ldin[z], ldout = jobs.ldout[z], koff = jobs.koff[z];
  int c0 = blockIdx.x * 32, r0 = blockIdx.y * 32;
  int tx = threadIdx.x, ty = threadIdx.y;
  for (int i = ty; i < 32; i += 8)
    tile[i][tx] = in[(size_t)(r0 + i) * ldin + c0 + tx];
  __syncthreads();
  for (int i = ty; i < 32; i += 8)
    out[(size_t)(c0 + i) * ldout + koff + r0 + tx] = (bf16_t)tile[tx][i];
}

// ---------------- bf16 transpose: vbuf [bh][s][d] -> vtb [bh][d][s] ----------------
__global__ void k_vtrans(const bf16_t* __restrict__ in, bf16_t* __restrict__ out) {
  __shared__ bf16_t t[64][72];
  int s0 = blockIdx.x * 64, d0 = blockIdx.y * 64, bh = blockIdx.z;
  const bf16_t* src = in + (size_t)bh * S_LEN * HD;
  bf16_t* dst = out + (size_t)bh * HD * S_LEN;
  int tid = threadIdx.x;
  for (int g = tid; g < 512; g += 256) {
    int r = g >> 3, cc = g & 7;
    *(bf16x8a*)&t[r][cc * 8] = *(const bf16x8a*)(src + (size_t)(s0 + r) * HD + d0 + cc * 8);
  }
  __syncthreads();
  for (int g = tid; g < 512; g += 256) {
    int dr = g >> 3, sc = g & 7;
    bf16x8 v;
#pragma unroll
    for (int j = 0; j < 8; j++) v[j] = t[sc * 8 + j][dr];
    *(bf16x8a*)(dst + (size_t)(d0 + dr) * S_LEN + s0 + sc * 8) = v;
  }
}

// ============ GEMM core: 2-barrier loop, BK=64 + row-XOR swizzle (v14) ============
// Round-8: BK=64 halved barriers (VALUBusy 16->12) but 128 B LDS rows made
// ds_read_b128 a 16-way conflict (1.57e7 -> 4.72e7) and net -9 us. v14 keeps
// BK=64 and swizzles: LDS slot (r,c) holds global granule c^(r&7) via
// pre-swizzled gld_lds SOURCE with linear dest (rule 21, the k_attn pattern).
// Reader fetches slot (kk*4+quad)^(l15&7); each 16-lane group spans all 8
// slots -> 2-way conflict = free (m136). row&7 == l15&7 for all fragment rows.

// ---------------- generic GEMM: A[M][K] x Bt[N][K] -> f32 out ----------------
template<int BM>
__global__ __launch_bounds__(256)
void k_gemm(const bf16_t* __restrict__ A, const bf16_t* __restrict__ Bt,
            float* __restrict__ outF, int M, int N, int K)
{
  __shared__ __align__(16) bf16_t As[BM * 64];
  __shared__ __align__(16) bf16_t Bs[128 * 64];
  const int tid  = threadIdx.x;
  const int lane = tid & 63, w = tid >> 6;
  const int quad = lane >> 4, l15 = lane & 15;
  const int m0 = blockIdx.y * BM, n0 = blockIdx.x * 128;
  constexpr int MI = BM / 32;             // m-frags per wave (4 or 2)
  constexpr int AG = BM / 32;             // A gld calls per thread (4 or 2)
  const int wm = (w >> 1) * (BM / 2);
  const int wn = (w & 1) * 64;

  // staging source offsets (element units), source pre-swizzled:
  // LDS slot (r, c) <- global granule c ^ (r & 7)
  int asrc[AG], bsrc[4];
#pragma unroll
  for (int j = 0; j < AG; j++) {
    int G = tid + 256 * j;
    int r = G >> 3, c = G & 7;
    asrc[j] = (m0 + r) * K + ((c ^ (r & 7)) * 8);
  }
#pragma unroll
  for (int j = 0; j < 4; j++) {
    int G = tid + 256 * j;
    int r = G >> 3, c = G & 7;
    bsrc[j] = (n0 + r) * K + ((c ^ (r & 7)) * 8);
  }
  // reader slot offsets per kk (elements): slot = (kk*4+quad) ^ (l15&7)
  const int rg0 = ((quad)     ^ (l15 & 7)) * 8;
  const int rg1 = ((4 + quad) ^ (l15 & 7)) * 8;

  f32x4 acc[MI][4];
#pragma unroll
  for (int i = 0; i < MI; i++)
#pragma unroll
    for (int j = 0; j < 4; j++) { f32x4 z = {0.f,0.f,0.f,0.f}; acc[i][j] = z; }

  for (int k0 = 0; k0 < K; k0 += 64) {
    __syncthreads();
#pragma unroll
    for (int j = 0; j < AG; j++)
      gld_lds16(A + asrc[j] + k0, As + j * 2048 + w * 512);
#pragma unroll
    for (int j = 0; j < 4; j++)
      gld_lds16(Bt + bsrc[j] + k0, Bs + j * 2048 + w * 512);
    __syncthreads();
#pragma unroll
    for (int kk = 0; kk < 2; kk++) {
      const int rg = kk ? rg1 : rg0;
      bf16x8 af[MI], bv[4];
#pragma unroll
      for (int i = 0; i < MI; i++)
        af[i] = *(const bf16x8a*)&As[(wm + i * 16 + l15) * 64 + rg];
#pragma unroll
      for (int j = 0; j < 4; j++)
        bv[j] = *(const bf16x8a*)&Bs[(wn + j * 16 + l15) * 64 + rg];
#pragma unroll
      for (int i = 0; i < MI; i++)
#pragma unroll
        for (int j = 0; j < 4; j++)
          acc[i][j] = mfma_bf16(af[i], bv[j], acc[i][j]);
    }
  }

#pragma unroll
  for (int i = 0; i < MI; i++)
#pragma unroll
    for (int j = 0; j < 4; j++)
#pragma unroll
      for (int r = 0; r < 4; r++) {
        int row = m0 + wm + i * 16 + quad * 4 + r;
        int col = n0 + wn + j * 16 + l15;
        outF[(size_t)row * N + col] = acc[i][j][r];
      }
}

// ---------------- fused QKV GEMM (BK=64 + swizzle, K-concat addend, RoPE) ----
__global__ __launch_bounds__(256)
void k_gemm_qkv(const bf16_t* __restrict__ hsB, const bf16_t* __restrict__ tsf,
                const bf16_t* __restrict__ wcat, bf16_t* __restrict__ outQKV,
                const float* __restrict__ tabC, const float* __restrict__ tabS)
{
  __shared__ __align__(16) bf16_t As[128 * 64];
  __shared__ __align__(16) bf16_t Bs[128 * 64];
  const int tid  = threadIdx.x;
  const int lane = tid & 63, w = tid >> 6;
  const int quad = lane >> 4, l15 = lane & 15;
  const int wi = blockIdx.x >> 4;                 // 0=Q 1=K 2=V
  const int n0 = (blockIdx.x & 15) * 128;         // head tile within weight
  const int m0 = blockIdx.y * 128;
  const int wm = (w >> 1) * 64;
  const bf16_t* Bt = wcat + (size_t)wi * HDIM * KCAT;
  bf16_t* outp = outQKV + (size_t)wi * 8388608;

  // staging source offsets, source pre-swizzled (slot c <- granule c^(r&7))
  int aoffh[4], aofft[4], boff[4];
#pragma unroll
  for (int j = 0; j < 4; j++) {
    int G = tid + 256 * j;
    int r = G >> 3, c = G & 7;
    int cs = (c ^ (r & 7)) * 8;
    aoffh[j] = (m0 + r) * HDIM + cs;
    aofft[j] = (m0 + r) * TSD  + cs;
    boff[j]  = (n0 + r) * KCAT + cs;
  }
  const int rg0 = ((quad)     ^ (l15 & 7)) * 8;
  const int rg1 = ((4 + quad) ^ (l15 & 7)) * 8;

  // paired column mapping (bijective over the 128-col tile)
  int col2[4];
#pragma unroll
  for (int j = 0; j < 4; j++)
    col2[j] = (w & 1) * 32 + (j & 1) * 16 + (j >> 1) * 64 + l15;

  f32x4 acc[4][4];
#pragma unroll
  for (int i = 0; i < 4; i++)
#pragma unroll
    for (int j = 0; j < 4; j++) { f32x4 z = {0.f,0.f,0.f,0.f}; acc[i][j] = z; }

  for (int k0 = 0; k0 < KCAT; k0 += 64) {
    __syncthreads();
    if (k0 < HDIM) {
#pragma unroll
      for (int j = 0; j < 4; j++)
        gld_lds16(hsB + aoffh[j] + k0, As + j * 2048 + w * 512);
    } else {
#pragma unroll
      for (int j = 0; j < 4; j++)
        gld_lds16(tsf + aofft[j] + (k0 - HDIM), As + j * 2048 + w * 512);
    }
#pragma unroll
    for (int j = 0; j < 4; j++)
      gld_lds16(Bt + boff[j] + k0, Bs + j * 2048 + w * 512);
    __syncthreads();
#pragma unroll
    for (int kk = 0; kk < 2; kk++) {
      const int rg = kk ? rg1 : rg0;
      bf16x8 af[4], bv[4];
#pragma unroll
      for (int i = 0; i < 4; i++)
        af[i] = *(const bf16x8a*)&As[(wm + i * 16 + l15) * 64 + rg];
#pragma unroll
      for (int j = 0; j < 4; j++)
        bv[j] = *(const bf16x8a*)&Bs[col2[j] * 64 + rg];
#pragma unroll
      for (int i = 0; i < 4; i++)
#pragma unroll
        for (int j = 0; j < 4; j++)
          acc[i][j] = mfma_bf16(af[i], bv[j], acc[i][j]);
    }
  }

  const int h = n0 >> 7;   // head index (n-tile == head)
  if (wi == 2) {
    // V: reshape store [b][h][s][d]
#pragma unroll
    for (int i = 0; i < 4; i++)
#pragma unroll
      for (int r = 0; r < 4; r++) {
        int row = m0 + wm + i * 16 + quad * 4 + r;
        int s = row & (S_LEN - 1), b = row >> 11;
        size_t obase = (((size_t)(b * NHEAD + h) * S_LEN) + s) * HD;
#pragma unroll
        for (int j = 0; j < 4; j++)
          outp[obase + col2[j]] = (bf16_t)acc[i][j][r];
      }
  } else {
    // Q/K: RoPE in f32, then store both halves of each (d, d+64) pair
#pragma unroll
    for (int i = 0; i < 4; i++)
#pragma unroll
      for (int r = 0; r < 4; r++) {
        int row = m0 + wm + i * 16 + quad * 4 + r;
        int s = row & (S_LEN - 1), b = row >> 11;
        size_t obase = (((size_t)(b * NHEAD + h) * S_LEN) + s) * HD;
#pragma unroll
        for (int j = 0; j < 2; j++) {
          int d = (w & 1) * 32 + j * 16 + l15;   // < 64
          float lo = acc[i][j][r];
          float hi = acc[i][j + 2][r];
          float c  = tabC[s * 64 + d];
          float sn = tabS[s * 64 + d];
          outp[obase + d]      = (bf16_t)(lo * c - hi * sn);
          outp[obase + d + 64] = (bf16_t)(hi * c + lo * sn);
        }
      }
  }
}

// ---------------- blend + rmsnorm + kth-threshold + relu ----------------
__global__ __launch_bounds__(256)
void k_tsproc(const float* __restrict__ ts, const float* __restrict__ lte,
              const float* __restrict__ wn, bf16_t* __restrict__ tsf)
{
  __shared__ float sv[TSD];
  __shared__ float red[4];
  int row = blockIdx.x;
  int t = threadIdx.x;
  const float* tr = ts  + (size_t)row * TSD;
  const float* lr = lte + (size_t)row * TSD;
  float v0 = 0.5f * tr[t] + 0.5f * lr[t];
  float v1 = 0.5f * tr[t + 256] + 0.5f * lr[t + 256];
  float ss = v0 * v0 + v1 * v1;
#pragma unroll
  for (int o = 32; o > 0; o >>= 1) ss += __shfl_down(ss, o);
  int lane = t & 63, wv = t >> 6;
  if (lane == 0) red[wv] = ss;
  __syncthreads();
  float tot = red[0] + red[1] + red[2] + red[3];
  float scl = rsqrtf(tot * (1.0f / TSD) + 1e-6f);
  float n0 = v0 * scl * wn[t];
  float n1 = v1 * scl * wn[t + 256];
  sv[t] = n0; sv[t + 256] = n1;
  __syncthreads();
  for (int k = 2; k <= TSD; k <<= 1) {
    for (int j = k >> 1; j > 0; j >>= 1) {
#pragma unroll
      for (int u = 0; u < 2; u++) {
        int idx = t + u * 256;
        int ixj = idx ^ j;
        if (ixj > idx) {
          float a = sv[idx], b = sv[ixj];
          bool up = ((idx & k) == 0);
          if ((a > b) == up) { sv[idx] = b; sv[ixj] = a; }
        }
      }
      __syncthreads();
    }
  }
  float kth = sv[KIDX];
  tsf[(size_t)row * TSD + t]       = (bf16_t)fmaxf(n0 - kth, 0.0f);
  tsf[(size_t)row * TSD + t + 256] = (bf16_t)fmaxf(n1 - kth, 0.0f);
}

// ---------------- RoPE tables: tab[s][d] = cos/sin(s * 10000^(-2d/128)) ----------------
__global__ void k_ropetab(float* __restrict__ tabC, float* __restrict__ tabS) {
  int gid = blockIdx.x * 256 + threadIdx.x;   // 2048*64
  int d = gid & 63, s = gid >> 6;
  float inv = powf(10000.0f, (float)(-2 * d) * (1.0f / 128.0f));
  float sn, c;
  sincosf((float)s * inv, &sn, &c);
  tabC[gid] = c; tabS[gid] = sn;
}

// ---------------- flash attention v7 (causal) ----------------
__global__ __launch_bounds__(256, 4)
void k_attn(const bf16_t* __restrict__ qb, const bf16_t* __restrict__ kb,
            const bf16_t* __restrict__ vtb, bf16_t* __restrict__ attnB)
{
  __shared__ __align__(16) bf16_t Kt[64 * 128];   // [key][d], swizzled granules
  __shared__ __align__(16) bf16_t Vt[128 * 64];   // [d][key], swizzled granules

  const int bid = blockIdx.x;
  const int bh  = (bid & 7) + 8 * (bid >> 8);     // same head -> same XCD (bid%8)
  static const int qmap[32] = {31,0,30,1,29,2,28,3,27,4,26,5,25,6,24,7,
                               23,8,22,9,21,10,20,11,19,12,18,13,17,14,16,15};
  const int q0 = qmap[((bid >> 3) + (bid >> 8)) & 31] * 64;

  const int tid = threadIdx.x;
  const int lane = tid & 63, w = tid >> 6;        // 4 waves
  const int quad = lane >> 4, l15 = lane & 15;

  const bf16_t* Q  = qb  + (size_t)bh * S_LEN * HD;
  const bf16_t* Kg = kb  + (size_t)bh * S_LEN * HD;
  const bf16_t* Vg = vtb + (size_t)bh * HD * S_LEN;   // [d][s]

  bf16x8 qf[4];
  {
    const bf16_t* qrow = Q + (size_t)(q0 + w * 16 + l15) * HD;
#pragma unroll
    for (int c = 0; c < 4; c++)
      qf[c] = *(const bf16x8a*)(qrow + c * 32 + quad * 8);
  }

  int kfo[4];
#pragma unroll
  for (int c = 0; c < 4; c++)
    kfo[c] = l15 * 128 + (((c * 4 + quad) ^ (l15 & 7)) * 8);
  int vfo[2];
#pragma unroll
  for (int kc = 0; kc < 2; kc++)
    vfo[kc] = l15 * 64 + (((kc * 4 + quad) ^ (l15 & 7)) * 8);

  int kSrc[4], vSrc[4];
#pragma unroll
  for (int j = 0; j < 4; j++) {
    int G  = (w * 4 + j) * 64 + lane;
    int r  = G >> 4, gl = G & 15;
    kSrc[j] = r * HD + ((gl ^ (r & 7)) * 8);
    int d  = G >> 3, vg = G & 7;
    vSrc[j] = d * S_LEN + ((vg ^ (d & 7)) * 8);
  }

  const int addrA = 4 * (l15 + 32 * (quad & 1));   // j=0..3 source lane
  const int addrB = addrA + 64;                    // j=4..7 source lane
  const bool selHi = (quad >> 1) != 0;             // quads 2,3 use pk[2kc+1]

  f32x4 o[8];
#pragma unroll
  for (int t8 = 0; t8 < 8; t8++) { f32x4 z = {0.f,0.f,0.f,0.f}; o[t8] = z; }
  float m_i = -1e30f, l_i = 0.0f;

  const float scale = 0.08838834764831845f;   // 1/sqrt(128)
  const int kEnd = q0;
  const int qrow_i = q0 + w * 16 + l15;

  for (int k0 = 0; k0 <= kEnd; k0 += 64) {
    {
      const bf16_t* Kgk = Kg + (size_t)k0 * HD;
      const bf16_t* Vgk = Vg + k0;
#pragma unroll
      for (int j = 0; j < 4; j++)
        gld_lds16(Kgk + kSrc[j], Kt + (w * 4 + j) * 512);
#pragma unroll
      for (int j = 0; j < 4; j++)
        gld_lds16(Vgk + vSrc[j], Vt + (w * 4 + j) * 512);
    }
    __syncthreads();   // barrier A: drains vmcnt, LDS writes visible

    f32x4 st_[4];
#pragma unroll
    for (int nt = 0; nt < 4; nt++) { f32x4 z = {0.f,0.f,0.f,0.f}; st_[nt] = z; }
    __builtin_amdgcn_s_setprio(1);
#pragma unroll
    for (int nt = 0; nt < 4; nt++)
#pragma unroll
      for (int c = 0; c < 4; c++) {
        bf16x8 kf = *(const bf16x8a*)(Kt + kfo[c] + nt * 2048);
        st_[nt] = mfma_bf16(kf, qf[c], st_[nt]);
      }
    __builtin_amdgcn_s_setprio(0);

    if (k0 == q0) {
#pragma unroll
      for (int nt = 0; nt < 4; nt++)
#pragma unroll
        for (int r = 0; r < 4; r++) {
          int key = k0 + nt * 16 + quad * 4 + r;
          float v = st_[nt][r] * scale;
          st_[nt][r] = (key > qrow_i) ? -1e9f : v;
        }
    } else {
#pragma unroll
      for (int nt = 0; nt < 4; nt++)
#pragma unroll
        for (int r = 0; r < 4; r++)
          st_[nt][r] *= scale;
    }

    float mx = st_[0][0];
#pragma unroll
    for (int nt = 0; nt < 4; nt++)
#pragma unroll
      for (int r = 0; r < 4; r++) mx = fmaxf(mx, st_[nt][r]);
    mx = fmaxf(mx, __shfl_xor(mx, 16));
    mx = fmaxf(mx, __shfl_xor(mx, 32));

    if (__ballot(mx > m_i + 8.0f)) {
      float mnew = fmaxf(m_i, mx);
      float alpha = __expf(m_i - mnew);
      m_i = mnew;
      l_i *= alpha;
#pragma unroll
      for (int t8 = 0; t8 < 8; t8++)
#pragma unroll
        for (int r = 0; r < 4; r++)
          o[t8][r] *= alpha;
    }

    float rs = 0.0f;
#pragma unroll
    for (int nt = 0; nt < 4; nt++)
#pragma unroll
      for (int r = 0; r < 4; r++) {
        float pv = __expf(st_[nt][r] - m_i);
        st_[nt][r] = pv;
        rs += pv;
      }
    rs += __shfl_xor(rs, 16);
    rs += __shfl_xor(rs, 32);
    l_i += rs;

    uint32_t pk[4][2];
#pragma unroll
    for (int nt = 0; nt < 4; nt++) {
      pk[nt][0] = pk2(st_[nt][0], st_[nt][1]);
      pk[nt][1] = pk2(st_[nt][2], st_[nt][3]);
    }

#pragma unroll
    for (int kc = 0; kc < 2; kc++) {
      uint32_t a0 = __builtin_amdgcn_ds_bpermute(addrA, (int)pk[2*kc][0]);
      uint32_t a1 = __builtin_amdgcn_ds_bpermute(addrA, (int)pk[2*kc][1]);
      uint32_t a2 = __builtin_amdgcn_ds_bpermute(addrB, (int)pk[2*kc][0]);
      uint32_t a3 = __builtin_amdgcn_ds_bpermute(addrB, (int)pk[2*kc][1]);
      uint32_t b0 = __builtin_amdgcn_ds_bpermute(addrA, (int)pk[2*kc+1][0]);
      uint32_t b1 = __builtin_amdgcn_ds_bpermute(addrA, (int)pk[2*kc+1][1]);
      uint32_t b2 = __builtin_amdgcn_ds_bpermute(addrB, (int)pk[2*kc+1][0]);
      uint32_t b3 = __builtin_amdgcn_ds_bpermute(addrB, (int)pk[2*kc+1][1]);
      union { bf16x8 v; uint32_t d[4]; } pf;
      pf.d[0] = selHi ? b0 : a0;
      pf.d[1] = selHi ? b1 : a1;
      pf.d[2] = selHi ? b2 : a2;
      pf.d[3] = selHi ? b3 : a3;
      __builtin_amdgcn_s_setprio(1);
#pragma unroll
      for (int t8 = 0; t8 < 8; t8++) {
        bf16x8 vf = *(const bf16x8a*)(Vt + vfo[kc] + t8 * 1024);
        o[t8] = mfma_bf16(vf, pf.v, o[t8]);
      }
      __builtin_amdgcn_s_setprio(0);
    }

    __syncthreads();   // barrier B
  }

  const int b = bh >> 4, h = bh & 15;
  const float rl = 1.0f / l_i;
  uint32_t* outp = (uint32_t*)(attnB + (size_t)(b * S_LEN + qrow_i) * HDIM + h * HD);
#pragma unroll
  for (int t8 = 0; t8 < 8; t8++)
#pragma unroll
    for (int pr = 0; pr < 2; pr++) {
      uint32_t v = pk2(o[t8][2*pr] * rl, o[t8][2*pr+1] * rl);
      outp[t8 * 8 + quad * 2 + pr] = v;
    }
}

// ---------------- launcher ----------------
extern "C" void kernel_launch(void* const* d_in, const int* in_sizes, int n_in,
                              void* d_out, int out_size, void* d_ws, size_t ws_size,
                              hipStream_t stream) {
  const float* hs    = (const float*)d_in[0];
  const float* lte   = (const float*)d_in[1];
  const float* Wq    = (const float*)d_in[2];
  const float* Wk    = (const float*)d_in[3];
  const float* Wv    = (const float*)d_in[4];
  const float* Wo    = (const float*)d_in[5];
  const float* Wts   = (const float*)d_in[6];
  const float* tsw   = (const float*)d_in[7];
  const float* Worig = (const float*)d_in[8];
  float* out = (float*)d_out;

  char* p = (char*)d_ws;
  bf16_t* hsB   = (bf16_t*)(p);
  bf16_t* wT    = (bf16_t*)(p + 16777216);
  float*  tsB   = (float*)(p + 25165824);
  bf16_t* tsf   = (bf16_t*)(p + 33554432);
  bf16_t* wcat  = (bf16_t*)(p + 37748736);
  bf16_t* attnB = (bf16_t*)(p + 37748736);         // alias (wcat dead)
  bf16_t* vtb   = (bf16_t*)(p + 54525952);         // alias (wcat dead)
  bf16_t* qbuf  = (bf16_t*)(p + 71303168);
  bf16_t* kbuf  = (bf16_t*)(p + 88080384);
  bf16_t* vbuf  = (bf16_t*)(p + 104857600);
  float*  tabC  = tsB;                             // tsB dead after k_tsproc
  float*  tabS  = tsB + 131072;
  bf16_t* wcatQ = wcat;
  bf16_t* wcatK = wcat + (size_t)HDIM * KCAT;
  bf16_t* wcatV = wcat + (size_t)2 * HDIM * KCAT;

  k_cvt<<<8192, 256, 0, stream>>>(hs, hsB, BROWS * HDIM);
  k_transpose<<<dim3(16, 64), dim3(32, 8), 0, stream>>>(Wts, wT, 512, 2048, 0);
  k_gemm<64><<<dim3(4, 64), 256, 0, stream>>>(hsB, wT, tsB, 4096, 512, 2048);
  k_tsproc<<<4096, 256, 0, stream>>>(tsB, lte, tsw, tsf);
  k_ropetab<<<512, 256, 0, stream>>>(tabC, tabS);

  {
    TJobs J;
    J.src[0] = Wq;    J.dst[0] = wcatQ; J.ldin[0] = 2048; J.ldout[0] = KCAT; J.koff[0] = 0;    J.nbx[0] = 64; J.nby[0] = 64;
    J.src[1] = Wk;    J.dst[1] = wcatK; J.ldin[1] = 2048; J.ldout[1] = KCAT; J.koff[1] = 0;    J.nbx[1] = 64; J.nby[1] = 64;
    J.src[2] = Wv;    J.dst[2] = wcatV; J.ldin[2] = 2048; J.ldout[2] = KCAT; J.koff[2] = 0;    J.nbx[2] = 64; J.nby[2] = 64;
    J.src[3] = Worig;        J.dst[3] = wcatQ; J.ldin[3] = 6144; J.ldout[3] = KCAT; J.koff[3] = 2048; J.nbx[3] = 64; J.nby[3] = 16;
    J.src[4] = Worig + 2048; J.dst[4] = wcatK; J.ldin[4] = 6144; J.ldout[4] = KCAT; J.koff[4] = 2048; J.nbx[4] = 64; J.nby[4] = 16;
    J.src[5] = Worig + 2048; J.dst[5] = wcatV; J.ldin[5] = 6144; J.ldout[5] = KCAT; J.koff[5] = 2048; J.nbx[5] = 64; J.nby[5] = 16;
    J.src[6] = Wo;    J.dst[6] = wT;    J.ldin[6] = 2048; J.ldout[6] = 2048; J.koff[6] = 0;    J.nbx[6] = 64; J.nby[6] = 64;
    k_transpose_multi<<<dim3(64, 64, 7), dim3(32, 8), 0, stream>>>(J);
  }

  k_gemm_qkv<<<dim3(48, 32), 256, 0, stream>>>(hsB, tsf, wcat, qbuf, tabC, tabS);
  k_vtrans<<<dim3(32, 2, 32), 256, 0, stream>>>(vbuf, vtb);
  k_attn<<<1024, 256, 0, stream>>>(qbuf, kbuf, vtb, attnB);
  k_gemm<128><<<dim3(16, 32), 256, 0, stream>>>(attnB, wT, out, 4096, 2048, 2048);
}